// Round 1
// baseline (3535.183 us; speedup 1.0000x reference)
//
#include <hip/hip_runtime.h>

// Problem constants (match reference setup_inputs)
#define NN 100000
#define NE 600000
#define NG 256
#define HID 128
#define BN_EPS 1e-5f

// ---------------- degree / dinv ----------------

__global__ __launch_bounds__(256) void deg_kernel(const int* __restrict__ dst, float* __restrict__ deg) {
    int e = blockIdx.x * blockDim.x + threadIdx.x;
    if (e < NE) atomicAdd(&deg[dst[e]], 1.0f);
}

__global__ __launch_bounds__(256) void dinv_kernel(float* deg) {
    int n = blockIdx.x * blockDim.x + threadIdx.x;
    if (n < NN) deg[n] = rsqrtf(deg[n] + 1.0f);
}

// ---------------- GCN layer 0 matmul (K=7) + self-loop/bias init ----------------
// Reads x [NN,7], writes hl [NN,128] and agg_init [NN,128].

__global__ __launch_bounds__(128) void gcn_mm0(const float* __restrict__ x,
                                               const float* __restrict__ W,
                                               const float* __restrict__ b,
                                               const float* __restrict__ dinv,
                                               float* __restrict__ hl,
                                               float* __restrict__ agg) {
    int j = threadIdx.x;  // 0..127 output feature
    float w[7];
#pragma unroll
    for (int k = 0; k < 7; k++) w[k] = W[k * HID + j];
    float bj = b[j];
    __shared__ float xs[8];
    for (int n = blockIdx.x; n < NN; n += gridDim.x) {
        if (j < 7) xs[j] = x[n * 7 + j];
        __syncthreads();
        float acc = 0.f;
#pragma unroll
        for (int k = 0; k < 7; k++) acc = fmaf(xs[k], w[k], acc);
        hl[(size_t)n * HID + j] = acc;
        float di = dinv[n];
        agg[(size_t)n * HID + j] = fmaf(acc, di * di, bj);
        __syncthreads();
    }
}

// ---------------- GCN layer matmul (K=128) + self-loop/bias init ----------------
// hin and agg may alias (in-place per-row is safe: row n is staged into LDS
// before row n of agg is written) -> no __restrict__ on those two.

__global__ __launch_bounds__(128) void gcn_mm128(const float* hin,
                                                 const float* __restrict__ W,
                                                 const float* __restrict__ b,
                                                 const float* __restrict__ dinv,
                                                 float* __restrict__ hl,
                                                 float* agg) {
    int j = threadIdx.x;  // output feature
    float w[HID];
#pragma unroll
    for (int k = 0; k < HID; k++) w[k] = W[k * HID + j];
    float bj = b[j];
    __shared__ float hs[HID];
    for (int n = blockIdx.x; n < NN; n += gridDim.x) {
        hs[j] = hin[(size_t)n * HID + j];
        __syncthreads();
        float acc = 0.f;
        const float4* hs4 = (const float4*)hs;
#pragma unroll
        for (int k4 = 0; k4 < HID / 4; k4++) {
            float4 hv = hs4[k4];
            acc = fmaf(hv.x, w[4 * k4 + 0], acc);
            acc = fmaf(hv.y, w[4 * k4 + 1], acc);
            acc = fmaf(hv.z, w[4 * k4 + 2], acc);
            acc = fmaf(hv.w, w[4 * k4 + 3], acc);
        }
        hl[(size_t)n * HID + j] = acc;
        float di = dinv[n];
        agg[(size_t)n * HID + j] = fmaf(acc, di * di, bj);
        __syncthreads();
    }
}

// ---------------- edge scatter: agg[dst] += hl[src] * dinv[src]*dinv[dst] ----------------
// 32 lanes per edge, float4 gather, 4 scalar atomics per lane.

__global__ __launch_bounds__(256) void scatter_kernel(const int* __restrict__ src,
                                                      const int* __restrict__ dst,
                                                      const float* __restrict__ dinv,
                                                      const float* __restrict__ hl,
                                                      float* __restrict__ agg) {
    int t = blockIdx.x * blockDim.x + threadIdx.x;
    int lane = t & 31;
    int e0 = t >> 5;
    int stride = (gridDim.x * blockDim.x) >> 5;
    const float4* hl4 = (const float4*)hl;
    for (int e = e0; e < NE; e += stride) {
        int s = src[e];
        int d = dst[e];
        float w = dinv[s] * dinv[d];
        float4 v = hl4[(size_t)s * 32 + lane];
        float* ap = &agg[(size_t)d * HID + lane * 4];
        atomicAdd(ap + 0, v.x * w);
        atomicAdd(ap + 1, v.y * w);
        atomicAdd(ap + 2, v.z * w);
        atomicAdd(ap + 3, v.w * w);
    }
}

// ---------------- BN (eval) + ReLU, in-place, float4 ----------------

__global__ __launch_bounds__(256) void bnrelu_kernel(float* __restrict__ h,
                                                     const float* __restrict__ gamma,
                                                     const float* __restrict__ beta,
                                                     const float* __restrict__ mean,
                                                     const float* __restrict__ var) {
    int t = blockIdx.x * blockDim.x + threadIdx.x;
    int total = NN * HID / 4;
    if (t >= total) return;
    int j4 = (t & 31) * 4;  // feature group
    const float4* g4 = (const float4*)(gamma);
    const float4* b4 = (const float4*)(beta);
    const float4* m4 = (const float4*)(mean);
    const float4* v4 = (const float4*)(var);
    float4 ga = g4[j4 / 4], be = b4[j4 / 4], me = m4[j4 / 4], va = v4[j4 / 4];
    float4* h4 = (float4*)h;
    float4 v = h4[t];
    float4 o;
    o.x = fmaxf((v.x - me.x) * (ga.x * rsqrtf(va.x + BN_EPS)) + be.x, 0.f);
    o.y = fmaxf((v.y - me.y) * (ga.y * rsqrtf(va.y + BN_EPS)) + be.y, 0.f);
    o.z = fmaxf((v.z - me.z) * (ga.z * rsqrtf(va.z + BN_EPS)) + be.z, 0.f);
    o.w = fmaxf((v.w - me.w) * (ga.w * rsqrtf(va.w + BN_EPS)) + be.w, 0.f);
    h4[t] = o;
}

// ---------------- global mean pool (batch is sorted) ----------------

__global__ __launch_bounds__(128) void pool_kernel(const float* __restrict__ h,
                                                   const int* __restrict__ batch,
                                                   float* __restrict__ lig) {
    int g = blockIdx.x;
    int j = threadIdx.x;
    __shared__ int se[2];
    if (j < 2) {
        int target = g + j;
        int lo = 0, hi = NN;
        while (lo < hi) {
            int mid = (lo + hi) >> 1;
            if (batch[mid] < target) lo = mid + 1; else hi = mid;
        }
        se[j] = lo;
    }
    __syncthreads();
    int start = se[0], end = se[1];
    float acc = 0.f;
    for (int n = start; n < end; n++) acc += h[(size_t)n * HID + j];
    float cnt = (float)(end - start);
    lig[g * HID + j] = acc / fmaxf(cnt, 1.0f);
}

// ---------------- pocket MLP: 28 -> 64 -> 64 ----------------

__global__ __launch_bounds__(64) void pocket_kernel(const float* __restrict__ pocket,
                                                    const float* __restrict__ pw1,
                                                    const float* __restrict__ pb1,
                                                    const float* __restrict__ pw2,
                                                    const float* __restrict__ pb2,
                                                    float* __restrict__ p) {
    int j = threadIdx.x;  // 0..63
    __shared__ float t1[64];
    float acc = pb1[j];
    for (int k = 0; k < 28; k++) acc = fmaf(pocket[k], pw1[k * 64 + j], acc);
    t1[j] = fmaxf(acc, 0.f);
    __syncthreads();
    float acc2 = pb2[j];
    for (int k = 0; k < 64; k++) acc2 = fmaf(t1[k], pw2[k * 64 + j], acc2);
    p[j] = acc2;
}

// ---------------- classifier: concat(lig, p) -> 96 -> 1 ----------------

__global__ __launch_bounds__(96) void cls_kernel(const float* __restrict__ lig,
                                                 const float* __restrict__ p,
                                                 const float* __restrict__ cw1,
                                                 const float* __restrict__ cb1,
                                                 const float* __restrict__ cw2,
                                                 const float* __restrict__ cb2,
                                                 float* __restrict__ out) {
    int g = blockIdx.x;
    int j = threadIdx.x;  // 0..95
    __shared__ float emb[192];
    __shared__ float hid[96];
    for (int k = j; k < HID; k += 96) emb[k] = lig[g * HID + k];
    for (int k = j; k < 64; k += 96) emb[HID + k] = p[k];
    __syncthreads();
    float acc = cb1[j];
    for (int k = 0; k < 192; k++) acc = fmaf(emb[k], cw1[k * 96 + j], acc);
    hid[j] = fmaxf(acc, 0.f) * cw2[j];
    __syncthreads();
    if (j == 0) {
        float s = cb2[0];
        for (int k = 0; k < 96; k++) s += hid[k];
        out[g] = s;
    }
}

extern "C" void kernel_launch(void* const* d_in, const int* in_sizes, int n_in,
                              void* d_out, int out_size, void* d_ws, size_t ws_size,
                              hipStream_t stream) {
    const float* x        = (const float*)d_in[0];
    const int*   eidx     = (const int*)d_in[1];
    const int*   batch    = (const int*)d_in[2];
    const float* pocket   = (const float*)d_in[3];
    const float* W0 = (const float*)d_in[4];  const float* b0 = (const float*)d_in[5];
    const float* W1 = (const float*)d_in[6];  const float* b1 = (const float*)d_in[7];
    const float* W2 = (const float*)d_in[8];  const float* b2 = (const float*)d_in[9];
    const float* bn_gamma = (const float*)d_in[10];
    const float* bn_beta  = (const float*)d_in[11];
    const float* bn_mean  = (const float*)d_in[12];
    const float* bn_var   = (const float*)d_in[13];
    const float* pw1 = (const float*)d_in[14]; const float* pb1 = (const float*)d_in[15];
    const float* pw2 = (const float*)d_in[16]; const float* pb2 = (const float*)d_in[17];
    const float* cw1 = (const float*)d_in[18]; const float* cb1 = (const float*)d_in[19];
    const float* cw2 = (const float*)d_in[20]; const float* cb2 = (const float*)d_in[21];
    float* out = (float*)d_out;

    // Workspace layout (floats):
    //   deg/dinv : NN
    //   A (hl)   : NN*HID
    //   B (agg/h): NN*HID
    //   lig      : NG*HID
    //   p        : 64
    float* ws  = (float*)d_ws;
    float* deg = ws;
    float* A   = ws + NN;
    float* B   = A + (size_t)NN * HID;
    float* lig = B + (size_t)NN * HID;
    float* pv  = lig + NG * HID;

    const int* srcp = eidx;
    const int* dstp = eidx + NE;

    hipMemsetAsync(deg, 0, NN * sizeof(float), stream);
    deg_kernel<<<(NE + 255) / 256, 256, 0, stream>>>(dstp, deg);
    dinv_kernel<<<(NN + 255) / 256, 256, 0, stream>>>(deg);

    const int MM_BLOCKS = 2048;
    const int SC_BLOCKS = 4096;
    const int BN_BLOCKS = (NN * HID / 4 + 255) / 256;

    // layer 0: x [NN,7] -> B
    gcn_mm0<<<MM_BLOCKS, 128, 0, stream>>>(x, W0, b0, deg, A, B);
    scatter_kernel<<<SC_BLOCKS, 256, 0, stream>>>(srcp, dstp, deg, A, B);
    bnrelu_kernel<<<BN_BLOCKS, 256, 0, stream>>>(B, bn_gamma + 0 * HID, bn_beta + 0 * HID,
                                                 bn_mean + 0 * HID, bn_var + 0 * HID);
    // layer 1
    gcn_mm128<<<MM_BLOCKS, 128, 0, stream>>>(B, W1, b1, deg, A, B);
    scatter_kernel<<<SC_BLOCKS, 256, 0, stream>>>(srcp, dstp, deg, A, B);
    bnrelu_kernel<<<BN_BLOCKS, 256, 0, stream>>>(B, bn_gamma + 1 * HID, bn_beta + 1 * HID,
                                                 bn_mean + 1 * HID, bn_var + 1 * HID);
    // layer 2
    gcn_mm128<<<MM_BLOCKS, 128, 0, stream>>>(B, W2, b2, deg, A, B);
    scatter_kernel<<<SC_BLOCKS, 256, 0, stream>>>(srcp, dstp, deg, A, B);
    bnrelu_kernel<<<BN_BLOCKS, 256, 0, stream>>>(B, bn_gamma + 2 * HID, bn_beta + 2 * HID,
                                                 bn_mean + 2 * HID, bn_var + 2 * HID);

    // pool -> lig [NG,HID]
    pool_kernel<<<NG, 128, 0, stream>>>(B, batch, lig);
    // pocket MLP -> pv [64]
    pocket_kernel<<<1, 64, 0, stream>>>(pocket, pw1, pb1, pw2, pb2, pv);
    // classifier -> out [NG]
    cls_kernel<<<NG, 96, 0, stream>>>(lig, pv, cw1, cb1, cw2, cb2, out);
}

// Round 2
// 896.202 us; speedup vs baseline: 3.9446x; 3.9446x over previous
//
#include <hip/hip_runtime.h>

// Problem constants (match reference setup_inputs)
#define NN 100000
#define NE 600000
#define NG 256
#define HID 128
#define BN_EPS 1e-5f

#define SCAN_TILE 1024
#define NTILES ((NN + SCAN_TILE - 1) / SCAN_TILE)  // 98

// ---------------- histogram of dst (in-degree) ----------------

__global__ __launch_bounds__(256) void hist_kernel(const int* __restrict__ dst, int* __restrict__ cnt) {
    int e = blockIdx.x * blockDim.x + threadIdx.x;
    if (e < NE) atomicAdd(&cnt[dst[e]], 1);
}

__global__ __launch_bounds__(256) void dinv_kernel(const int* __restrict__ cnt, float* __restrict__ dinv) {
    int n = blockIdx.x * blockDim.x + threadIdx.x;
    if (n < NN) dinv[n] = rsqrtf((float)cnt[n] + 1.0f);
}

// ---------------- 2-level exclusive scan of cnt -> row_start ----------------
// scan_a: per-tile (1024 elems, 256 thr x 4) local exclusive scan into rs, tile sum into tsum.

__global__ __launch_bounds__(256) void scan_a(const int* __restrict__ cnt, int* __restrict__ rs,
                                              int* __restrict__ tsum) {
    __shared__ int s[256];
    int t = threadIdx.x;
    int base = blockIdx.x * SCAN_TILE;
    int idx = base + t * 4;
    int v0 = (idx + 0 < NN) ? cnt[idx + 0] : 0;
    int v1 = (idx + 1 < NN) ? cnt[idx + 1] : 0;
    int v2 = (idx + 2 < NN) ? cnt[idx + 2] : 0;
    int v3 = (idx + 3 < NN) ? cnt[idx + 3] : 0;
    int local = v0 + v1 + v2 + v3;
    s[t] = local;
    __syncthreads();
    for (int off = 1; off < 256; off <<= 1) {
        int x = (t >= off) ? s[t - off] : 0;
        __syncthreads();
        s[t] += x;
        __syncthreads();
    }
    int pre = s[t] - local;  // exclusive prefix within tile
    if (t == 255) tsum[blockIdx.x] = s[255];
    if (idx + 0 < NN) rs[idx + 0] = pre; pre += v0;
    if (idx + 1 < NN) rs[idx + 1] = pre; pre += v1;
    if (idx + 2 < NN) rs[idx + 2] = pre; pre += v2;
    if (idx + 3 < NN) rs[idx + 3] = pre;
}

// scan_b: single block scans tile sums (exclusive, in place). NTILES <= 128.
__global__ __launch_bounds__(128) void scan_b(int* __restrict__ tsum) {
    __shared__ int s[128];
    int t = threadIdx.x;
    int v = (t < NTILES) ? tsum[t] : 0;
    s[t] = v;
    __syncthreads();
    for (int off = 1; off < 128; off <<= 1) {
        int x = (t >= off) ? s[t - off] : 0;
        __syncthreads();
        s[t] += x;
        __syncthreads();
    }
    if (t < NTILES) tsum[t] = s[t] - v;  // exclusive
}

// scan_c: add tile offsets; also initialize cursor copy and rs[NN].
__global__ __launch_bounds__(256) void scan_c(int* __restrict__ rs, const int* __restrict__ tsum,
                                              int* __restrict__ cursor) {
    int t = threadIdx.x;
    int base = blockIdx.x * SCAN_TILE;
    int off = tsum[blockIdx.x];
    for (int k = 0; k < 4; k++) {
        int idx = base + t * 4 + k;
        if (idx < NN) {
            int v = rs[idx] + off;
            rs[idx] = v;
            cursor[idx] = v;
        }
    }
    if (blockIdx.x == 0 && t == 0) rs[NN] = NE;
}

// ---------------- bucket edges by dst ----------------

__global__ __launch_bounds__(256) void bucket_kernel(const int* __restrict__ src, const int* __restrict__ dst,
                                                     int* __restrict__ cursor, int* __restrict__ esrc) {
    int e = blockIdx.x * blockDim.x + threadIdx.x;
    if (e < NE) {
        int pos = atomicAdd(&cursor[dst[e]], 1);
        esrc[pos] = src[e];
    }
}

// ---------------- GCN layer 0 matmul (K=7): x [NN,7] @ W0 [7,128] -> hl ----------------

__global__ __launch_bounds__(128) void gcn_mm0(const float* __restrict__ x,
                                               const float* __restrict__ W,
                                               float* __restrict__ hl) {
    int j = threadIdx.x;
    float w[7];
#pragma unroll
    for (int k = 0; k < 7; k++) w[k] = W[k * HID + j];
    for (int n = blockIdx.x; n < NN; n += gridDim.x) {
        float acc = 0.f;
#pragma unroll
        for (int k = 0; k < 7; k++) acc = fmaf(x[n * 7 + k], w[k], acc);
        hl[(size_t)n * HID + j] = acc;
    }
}

// ---------------- GCN layer matmul (K=128): h [NN,128] @ W [128,128] -> hl ----------------

__global__ __launch_bounds__(128) void gcn_mm128(const float* __restrict__ hin,
                                                 const float* __restrict__ W,
                                                 float* __restrict__ hl) {
    int j = threadIdx.x;
    float w[HID];
#pragma unroll
    for (int k = 0; k < HID; k++) w[k] = W[k * HID + j];
    __shared__ float hs[HID];
    for (int n = blockIdx.x; n < NN; n += gridDim.x) {
        __syncthreads();
        hs[j] = hin[(size_t)n * HID + j];
        __syncthreads();
        float acc = 0.f;
        const float4* hs4 = (const float4*)hs;
#pragma unroll
        for (int k4 = 0; k4 < HID / 4; k4++) {
            float4 hv = hs4[k4];
            acc = fmaf(hv.x, w[4 * k4 + 0], acc);
            acc = fmaf(hv.y, w[4 * k4 + 1], acc);
            acc = fmaf(hv.z, w[4 * k4 + 2], acc);
            acc = fmaf(hv.w, w[4 * k4 + 3], acc);
        }
        hl[(size_t)n * HID + j] = acc;
    }
}

// ---------------- fused gather-aggregate + self-loop + bias + BN + ReLU ----------------
// out[n] = relu(BN( sum_{e in in(n)} hl[src_e]*dinv[src_e]*dinv[n] + hl[n]*dinv[n]^2 + b ))
// 256 threads = 2 nodes per block.

__global__ __launch_bounds__(256) void gather_bn(const float* __restrict__ hl,
                                                 const int* __restrict__ rs,
                                                 const int* __restrict__ esrc,
                                                 const float* __restrict__ dinv,
                                                 const float* __restrict__ b,
                                                 const float* __restrict__ gamma,
                                                 const float* __restrict__ beta,
                                                 const float* __restrict__ mean,
                                                 const float* __restrict__ var,
                                                 float* __restrict__ out) {
    int n = blockIdx.x * 2 + (threadIdx.x >> 7);
    int j = threadIdx.x & 127;
    if (n >= NN) return;
    float di = dinv[n];
    float acc = fmaf(hl[(size_t)n * HID + j], di * di, b[j]);
    int e0 = rs[n], e1 = rs[n + 1];
    for (int e = e0; e < e1; e++) {
        int s = esrc[e];
        float w = dinv[s] * di;
        acc = fmaf(hl[(size_t)s * HID + j], w, acc);
    }
    float scale = gamma[j] * rsqrtf(var[j] + BN_EPS);
    out[(size_t)n * HID + j] = fmaxf(fmaf(acc - mean[j], scale, beta[j]), 0.f);
}

// ---------------- global mean pool (batch is sorted) ----------------

__global__ __launch_bounds__(128) void pool_kernel(const float* __restrict__ h,
                                                   const int* __restrict__ batch,
                                                   float* __restrict__ lig) {
    int g = blockIdx.x;
    int j = threadIdx.x;
    __shared__ int se[2];
    if (j < 2) {
        int target = g + j;
        int lo = 0, hi = NN;
        while (lo < hi) {
            int mid = (lo + hi) >> 1;
            if (batch[mid] < target) lo = mid + 1; else hi = mid;
        }
        se[j] = lo;
    }
    __syncthreads();
    int start = se[0], end = se[1];
    float acc = 0.f;
    for (int n = start; n < end; n++) acc += h[(size_t)n * HID + j];
    float cnt = (float)(end - start);
    lig[g * HID + j] = acc / fmaxf(cnt, 1.0f);
}

// ---------------- pocket MLP: 28 -> 64 -> 64 ----------------

__global__ __launch_bounds__(64) void pocket_kernel(const float* __restrict__ pocket,
                                                    const float* __restrict__ pw1,
                                                    const float* __restrict__ pb1,
                                                    const float* __restrict__ pw2,
                                                    const float* __restrict__ pb2,
                                                    float* __restrict__ p) {
    int j = threadIdx.x;
    __shared__ float t1[64];
    float acc = pb1[j];
    for (int k = 0; k < 28; k++) acc = fmaf(pocket[k], pw1[k * 64 + j], acc);
    t1[j] = fmaxf(acc, 0.f);
    __syncthreads();
    float acc2 = pb2[j];
    for (int k = 0; k < 64; k++) acc2 = fmaf(t1[k], pw2[k * 64 + j], acc2);
    p[j] = acc2;
}

// ---------------- classifier: concat(lig, p) -> 96 -> 1 ----------------

__global__ __launch_bounds__(96) void cls_kernel(const float* __restrict__ lig,
                                                 const float* __restrict__ p,
                                                 const float* __restrict__ cw1,
                                                 const float* __restrict__ cb1,
                                                 const float* __restrict__ cw2,
                                                 const float* __restrict__ cb2,
                                                 float* __restrict__ out) {
    int g = blockIdx.x;
    int j = threadIdx.x;
    __shared__ float emb[192];
    __shared__ float hid[96];
    for (int k = j; k < HID; k += 96) emb[k] = lig[g * HID + k];
    for (int k = j; k < 64; k += 96) emb[HID + k] = p[k];
    __syncthreads();
    float acc = cb1[j];
    for (int k = 0; k < 192; k++) acc = fmaf(emb[k], cw1[k * 96 + j], acc);
    hid[j] = fmaxf(acc, 0.f) * cw2[j];
    __syncthreads();
    if (j == 0) {
        float s = cb2[0];
        for (int k = 0; k < 96; k++) s += hid[k];
        out[g] = s;
    }
}

extern "C" void kernel_launch(void* const* d_in, const int* in_sizes, int n_in,
                              void* d_out, int out_size, void* d_ws, size_t ws_size,
                              hipStream_t stream) {
    const float* x        = (const float*)d_in[0];
    const int*   eidx     = (const int*)d_in[1];
    const int*   batch    = (const int*)d_in[2];
    const float* pocket   = (const float*)d_in[3];
    const float* W0 = (const float*)d_in[4];
    const float* b0 = (const float*)d_in[5];
    const float* W1 = (const float*)d_in[6];
    const float* b1 = (const float*)d_in[7];
    const float* W2 = (const float*)d_in[8];
    const float* b2 = (const float*)d_in[9];
    const float* bn_gamma = (const float*)d_in[10];
    const float* bn_beta  = (const float*)d_in[11];
    const float* bn_mean  = (const float*)d_in[12];
    const float* bn_var   = (const float*)d_in[13];
    const float* pw1 = (const float*)d_in[14]; const float* pb1 = (const float*)d_in[15];
    const float* pw2 = (const float*)d_in[16]; const float* pb2 = (const float*)d_in[17];
    const float* cw1 = (const float*)d_in[18]; const float* cb1 = (const float*)d_in[19];
    const float* cw2 = (const float*)d_in[20]; const float* cb2 = (const float*)d_in[21];
    float* out = (float*)d_out;

    // Workspace layout (4-byte units, A/B 16B-aligned):
    float* ws   = (float*)d_ws;
    float* dinv = ws;                                   // NN floats
    int*   cnt  = (int*)(ws + NN);                      // NN ints (hist, then cursor)
    int*   rs   = cnt + NN;                             // NN+1 ints (row_start)
    int*   tsum = rs + NN + 1;                          // 128 ints
    int*   esrc = tsum + 128;                           // NE ints
    size_t head = (size_t)NN + NN + (NN + 1) + 128 + NE;  // = 900229
    head = (head + 3) & ~(size_t)3;                     // 16B align
    float* A    = ws + head;                            // NN*HID
    float* B    = A + (size_t)NN * HID;                 // NN*HID
    float* lig  = B + (size_t)NN * HID;                 // NG*HID
    float* pv   = lig + (size_t)NG * HID;               // 64

    const int* srcp = eidx;
    const int* dstp = eidx + NE;

    // ---- build CSR (by dst) + dinv ----
    hipMemsetAsync(cnt, 0, NN * sizeof(int), stream);
    hist_kernel<<<(NE + 255) / 256, 256, 0, stream>>>(dstp, cnt);
    dinv_kernel<<<(NN + 255) / 256, 256, 0, stream>>>(cnt, dinv);
    scan_a<<<NTILES, 256, 0, stream>>>(cnt, rs, tsum);
    scan_b<<<1, 128, 0, stream>>>(tsum);
    scan_c<<<NTILES, 256, 0, stream>>>(rs, tsum, cnt);  // cnt becomes cursor
    bucket_kernel<<<(NE + 255) / 256, 256, 0, stream>>>(srcp, dstp, cnt, esrc);

    const int MM_BLOCKS = 2048;
    const int GA_BLOCKS = (NN + 1) / 2;

    // layer 0
    gcn_mm0<<<MM_BLOCKS, 128, 0, stream>>>(x, W0, A);
    gather_bn<<<GA_BLOCKS, 256, 0, stream>>>(A, rs, esrc, dinv, b0,
                                             bn_gamma + 0 * HID, bn_beta + 0 * HID,
                                             bn_mean + 0 * HID, bn_var + 0 * HID, B);
    // layer 1
    gcn_mm128<<<MM_BLOCKS, 128, 0, stream>>>(B, W1, A);
    gather_bn<<<GA_BLOCKS, 256, 0, stream>>>(A, rs, esrc, dinv, b1,
                                             bn_gamma + 1 * HID, bn_beta + 1 * HID,
                                             bn_mean + 1 * HID, bn_var + 1 * HID, B);
    // layer 2
    gcn_mm128<<<MM_BLOCKS, 128, 0, stream>>>(B, W2, A);
    gather_bn<<<GA_BLOCKS, 256, 0, stream>>>(A, rs, esrc, dinv, b2,
                                             bn_gamma + 2 * HID, bn_beta + 2 * HID,
                                             bn_mean + 2 * HID, bn_var + 2 * HID, B);

    // pool -> lig
    pool_kernel<<<NG, 128, 0, stream>>>(B, batch, lig);
    // pocket MLP
    pocket_kernel<<<1, 64, 0, stream>>>(pocket, pw1, pb1, pw2, pb2, pv);
    // classifier
    cls_kernel<<<NG, 96, 0, stream>>>(lig, pv, cw1, cb1, cw2, cb2, out);
}